// Round 1
// baseline (68.896 us; speedup 1.0000x reference)
//
#include <hip/hip_runtime.h>

// Problem constants (B=1, C=3, T=3, H=2160, W=3840), all fp32.
#define W_DIM 3840
#define H_DIM 2160
#define C_DIM 3

// out[c,h,w] = temporal blend of horizontally-shifted frames.
// alpha = 0 on even rows (=> out = shifted cur); on odd rows alpha in [-1,1]
// selects prev (a<0) or nxt (a>0). Branch is uniform per row (per blockIdx.y).
__global__ __launch_bounds__(256) void rts_kernel(
    const float* __restrict__ fs,          // (C, T=3, H, W)
    const float* __restrict__ row_shifts,  // (H,)
    const float* __restrict__ rts,         // (H/2,)
    float* __restrict__ out)               // (C, H, W)
{
    const int w = blockIdx.x * 256 + threadIdx.x;   // W = 15 * 256, exact
    const int h = blockIdx.y;
    const int c = blockIdx.z;

    const float shift = row_shifts[h];
    const float pos = (float)w - shift;
    const float x0f = floorf(pos);
    const float w1 = pos - x0f;
    const int x0i = (int)x0f;
    const int x1i = x0i + 1;
    const float m0 = (x0i >= 0 && x0i < W_DIM) ? 1.0f : 0.0f;
    const float m1 = (x1i >= 0 && x1i < W_DIM) ? 1.0f : 0.0f;
    const int i0 = min(max(x0i, 0), W_DIM - 1);
    const int i1 = min(max(x1i, 0), W_DIM - 1);

    const float c0 = (1.0f - w1) * m0;
    const float c1 = w1 * m1;

    // Base of the (c, t=1, h) row.
    const size_t frame_stride = (size_t)H_DIM * W_DIM;
    const float* curRow = fs + ((size_t)c * 3 + 1) * frame_stride + (size_t)h * W_DIM;

    const float cur = c0 * curRow[i0] + c1 * curRow[i1];

    float a = 0.0f;
    if (h & 1) a = rts[h >> 1];

    float result;
    if (a < 0.0f) {
        const float* prevRow = curRow - frame_stride;   // t = 0
        const float prev = c0 * prevRow[i0] + c1 * prevRow[i1];
        result = (1.0f + a) * cur - a * prev;
    } else if (a > 0.0f) {
        const float* nxtRow = curRow + frame_stride;    // t = 2
        const float nxt = c0 * nxtRow[i0] + c1 * nxtRow[i1];
        result = (1.0f - a) * cur + a * nxt;
    } else {
        result = cur;                                    // alpha == 0 (all even rows)
    }

    out[((size_t)c * H_DIM + h) * W_DIM + w] = result;
}

extern "C" void kernel_launch(void* const* d_in, const int* in_sizes, int n_in,
                              void* d_out, int out_size, void* d_ws, size_t ws_size,
                              hipStream_t stream) {
    const float* fs  = (const float*)d_in[0];
    const float* rs  = (const float*)d_in[1];
    const float* rt  = (const float*)d_in[2];
    float* out = (float*)d_out;

    dim3 grid(W_DIM / 256, H_DIM, C_DIM);   // (15, 2160, 3)
    rts_kernel<<<grid, 256, 0, stream>>>(fs, rs, rt, out);
}

// Round 2
// 53.888 us; speedup vs baseline: 1.2785x; 1.2785x over previous
//
#include <hip/hip_runtime.h>

// Problem constants (B=1, C=3, T=3, H=2160, W=3840), all fp32.
#define W_DIM 3840
#define H_DIM 2160
#define C_DIM 3
#define TPB 192                    // 3 waves; 192*4 = 768 cols per block
#define COLS_PER_BLOCK (TPB * 4)   // 768 ; 3840 / 768 = 5 blocks per row

// Select 5 consecutive elements a[r..r+4] out of two aligned float4s and
// apply the horizontal blend. r is uniform per row -> uniform branch.
__device__ __forceinline__ float4 hblend(float4 lo, float4 hi, int r,
                                         float c0, float c1) {
    float a0, a1, a2, a3, a4;
    switch (r) {
        case 0:  a0 = lo.x; a1 = lo.y; a2 = lo.z; a3 = lo.w; a4 = hi.x; break;
        case 1:  a0 = lo.y; a1 = lo.z; a2 = lo.w; a3 = hi.x; a4 = hi.y; break;
        case 2:  a0 = lo.z; a1 = lo.w; a2 = hi.x; a3 = hi.y; a4 = hi.z; break;
        default: a0 = lo.w; a1 = hi.x; a2 = hi.y; a3 = hi.z; a4 = hi.w; break;
    }
    return make_float4(c0 * a0 + c1 * a1,
                       c0 * a1 + c1 * a2,
                       c0 * a2 + c1 * a3,
                       c0 * a3 + c1 * a4);
}

__global__ __launch_bounds__(TPB) void rts_kernel(
    const float* __restrict__ fs,          // (C, T=3, H, W)
    const float* __restrict__ row_shifts,  // (H,)
    const float* __restrict__ rts,         // (H/2,)
    float* __restrict__ out)               // (C, H, W)
{
    const int h  = blockIdx.y;
    const int c  = blockIdx.z;
    const int blk_w0 = blockIdx.x * COLS_PER_BLOCK;
    const int w0 = blk_w0 + threadIdx.x * 4;

    // pos = w - shift ; x0 = w + K with K = floor(-shift) (per-row constant),
    // w1 = frac(-shift) (per-row constant).
    const float shift = row_shifts[h];
    const float negs  = -shift;
    const float Kf    = floorf(negs);
    const float w1    = negs - Kf;
    const int   K     = (int)Kf;
    const float c0    = 1.0f - w1;
    const float c1    = w1;

    // Temporal blend: out = (1-|a|)*cur + |a|*oth, oth = prev if a<0 else nxt.
    float a = 0.0f;
    if (h & 1) a = rts[h >> 1];
    const float ab = fabsf(a);

    const size_t frame_stride = (size_t)H_DIM * W_DIM;
    const float* curRow = fs + ((size_t)c * 3 + 1) * frame_stride + (size_t)h * W_DIM;
    const float* othRow = (a < 0.0f) ? (curRow - frame_stride)   // prev
                                     : (curRow + frame_stride);  // nxt

    // Block-uniform interior check: every needed index in [0, W).
    const bool fast = (blk_w0 + K >= 0) &&
                      (blk_w0 + COLS_PER_BLOCK + K <= W_DIM - 1);

    float4 result;
    if (fast) {
        const int base = w0 + K;          // >= 0 in fast path
        const int A    = base & ~3;       // 16B-aligned float index
        const int r    = base & 3;        // row-uniform

        const float4 clo = *(const float4*)(curRow + A);
        const float4 chi = *(const float4*)(curRow + A + 4);
        result = hblend(clo, chi, r, c0, c1);

        if (ab != 0.0f) {
            const float4 olo = *(const float4*)(othRow + A);
            const float4 ohi = *(const float4*)(othRow + A + 4);
            const float4 oth = hblend(olo, ohi, r, c0, c1);
            result.x = (1.0f - ab) * result.x + ab * oth.x;
            result.y = (1.0f - ab) * result.y + ab * oth.y;
            result.z = (1.0f - ab) * result.z + ab * oth.z;
            result.w = (1.0f - ab) * result.w + ab * oth.w;
        }
    } else {
        // Edge blocks: scalar path with clamping + masks.
        float r4[4];
#pragma unroll
        for (int j = 0; j < 4; ++j) {
            const int x0i = w0 + j + K;
            const int x1i = x0i + 1;
            const float m0 = (x0i >= 0 && x0i < W_DIM) ? 1.0f : 0.0f;
            const float m1 = (x1i >= 0 && x1i < W_DIM) ? 1.0f : 0.0f;
            const int i0 = min(max(x0i, 0), W_DIM - 1);
            const int i1 = min(max(x1i, 0), W_DIM - 1);
            float v = c0 * m0 * curRow[i0] + c1 * m1 * curRow[i1];
            if (ab != 0.0f) {
                const float o = c0 * m0 * othRow[i0] + c1 * m1 * othRow[i1];
                v = (1.0f - ab) * v + ab * o;
            }
            r4[j] = v;
        }
        result = make_float4(r4[0], r4[1], r4[2], r4[3]);
    }

    *(float4*)(out + ((size_t)c * H_DIM + h) * W_DIM + w0) = result;
}

extern "C" void kernel_launch(void* const* d_in, const int* in_sizes, int n_in,
                              void* d_out, int out_size, void* d_ws, size_t ws_size,
                              hipStream_t stream) {
    const float* fs = (const float*)d_in[0];
    const float* rs = (const float*)d_in[1];
    const float* rt = (const float*)d_in[2];
    float* out = (float*)d_out;

    dim3 grid(W_DIM / COLS_PER_BLOCK, H_DIM, C_DIM);   // (5, 2160, 3)
    rts_kernel<<<grid, TPB, 0, stream>>>(fs, rs, rt, out);
}

// Round 4
// 44.758 us; speedup vs baseline: 1.5393x; 1.2040x over previous
//
#include <hip/hip_runtime.h>

// Problem constants (B=1, C=3, T=3, H=2160, W=3840), all fp32.
#define W_DIM 3840
#define H_DIM 2160
#define C_DIM 3
#define TPB 192
#define NSEG 5            // 192 threads * 5 float4 * 4 = 3840 cols = one full row

typedef float f32x4 __attribute__((ext_vector_type(4)));

// Select 5 consecutive elements a[r..r+4] out of two aligned float4s and
// apply horizontal lerp. r is uniform per row -> uniform branch.
__device__ __forceinline__ f32x4 hblend(f32x4 lo, f32x4 hi, int r,
                                        float c0, float c1) {
    float a0, a1, a2, a3, a4;
    switch (r) {
        case 0:  a0 = lo.x; a1 = lo.y; a2 = lo.z; a3 = lo.w; a4 = hi.x; break;
        case 1:  a0 = lo.y; a1 = lo.z; a2 = lo.w; a3 = hi.x; a4 = hi.y; break;
        case 2:  a0 = lo.z; a1 = lo.w; a2 = hi.x; a3 = hi.y; a4 = hi.z; break;
        default: a0 = lo.w; a1 = hi.x; a2 = hi.y; a3 = hi.z; a4 = hi.w; break;
    }
    f32x4 out;
    out.x = c0 * a0 + c1 * a1;
    out.y = c0 * a1 + c1 * a2;
    out.z = c0 * a2 + c1 * a3;
    out.w = c0 * a3 + c1 * a4;
    return out;
}

// Scalar clamped+masked path for row-edge segments (few threads per row).
__device__ __forceinline__ f32x4 hblend_slow(const float* __restrict__ row,
                                             int base, float c0, float c1) {
    f32x4 res;
    float r4[4];
#pragma unroll
    for (int jj = 0; jj < 4; ++jj) {
        const int x0i = base + jj;
        const int x1i = x0i + 1;
        const float m0 = (x0i >= 0 && x0i < W_DIM) ? 1.0f : 0.0f;
        const float m1 = (x1i >= 0 && x1i < W_DIM) ? 1.0f : 0.0f;
        const int i0 = min(max(x0i, 0), W_DIM - 1);
        const int i1 = min(max(x1i, 0), W_DIM - 1);
        r4[jj] = c0 * m0 * row[i0] + c1 * m1 * row[i1];
    }
    res.x = r4[0]; res.y = r4[1]; res.z = r4[2]; res.w = r4[3];
    return res;
}

__global__ __launch_bounds__(TPB) void rts_kernel(
    const float* __restrict__ fs,          // (C, T=3, H, W)
    const float* __restrict__ row_shifts,  // (H,)
    const float* __restrict__ rts,         // (H/2,)
    float* __restrict__ out)               // (C, H, W)
{
    const int h   = blockIdx.x;
    const int c   = blockIdx.y;
    const int tid = threadIdx.x;

    // Per-row constants: x0 = w + K, w1 = frac(-shift).
    const float shift = row_shifts[h];
    const float negs  = -shift;
    const float Kf    = floorf(negs);
    const float w1    = negs - Kf;
    const int   K     = (int)Kf;
    const float c0    = 1.0f - w1;
    const float c1    = w1;
    const int   r     = K & 3;             // two's-complement low bits == K mod 4

    float a = 0.0f;
    if (h & 1) a = rts[h >> 1];
    const float ab = fabsf(a);
    const float cw = 1.0f - ab;

    const size_t frame_stride = (size_t)H_DIM * W_DIM;
    const float* curRow = fs + ((size_t)c * 3 + 1) * frame_stride + (size_t)h * W_DIM;
    const float* othRow = (a < 0.0f) ? (curRow - frame_stride)   // prev
                                     : (curRow + frame_stride);  // nxt
    float* outRow = out + ((size_t)c * H_DIM + h) * W_DIM;

    if (ab == 0.0f) {
        // Even rows (and alpha==0): pure shifted copy of cur.
#pragma unroll
        for (int j = 0; j < NSEG; ++j) {
            const int w0   = 4 * (tid + j * TPB);
            const int base = w0 + K;
            f32x4 res;
            if (base >= 0 && base <= W_DIM - 5) {
                const int A = base & ~3;
                const f32x4 clo = *(const f32x4*)(curRow + A);
                const f32x4 chi = *(const f32x4*)(curRow + A + 4);
                res = hblend(clo, chi, r, c0, c1);
            } else {
                res = hblend_slow(curRow, base, c0, c1);
            }
            __builtin_nontemporal_store(res, (f32x4*)(outRow + w0));
        }
    } else {
        // Odd rows: blend shifted cur with shifted prev/nxt.
#pragma unroll
        for (int j = 0; j < NSEG; ++j) {
            const int w0   = 4 * (tid + j * TPB);
            const int base = w0 + K;
            f32x4 res;
            if (base >= 0 && base <= W_DIM - 5) {
                const int A = base & ~3;
                const f32x4 clo = *(const f32x4*)(curRow + A);
                const f32x4 chi = *(const f32x4*)(curRow + A + 4);
                const f32x4 olo = *(const f32x4*)(othRow + A);
                const f32x4 ohi = *(const f32x4*)(othRow + A + 4);
                const f32x4 cu  = hblend(clo, chi, r, c0, c1);
                const f32x4 ot  = hblend(olo, ohi, r, c0, c1);
                res = cw * cu + ab * ot;
            } else {
                const f32x4 cu = hblend_slow(curRow, base, c0, c1);
                const f32x4 ot = hblend_slow(othRow, base, c0, c1);
                res = cw * cu + ab * ot;
            }
            __builtin_nontemporal_store(res, (f32x4*)(outRow + w0));
        }
    }
}

extern "C" void kernel_launch(void* const* d_in, const int* in_sizes, int n_in,
                              void* d_out, int out_size, void* d_ws, size_t ws_size,
                              hipStream_t stream) {
    const float* fs = (const float*)d_in[0];
    const float* rs = (const float*)d_in[1];
    const float* rt = (const float*)d_in[2];
    float* out = (float*)d_out;

    dim3 grid(H_DIM, C_DIM);   // one block per (row, channel)
    rts_kernel<<<grid, TPB, 0, stream>>>(fs, rs, rt, out);
}

// Round 5
// 44.403 us; speedup vs baseline: 1.5516x; 1.0080x over previous
//
#include <hip/hip_runtime.h>

// Problem constants (B=1, C=3, T=3, H=2160, W=3840), all fp32.
#define W_DIM 3840
#define H_DIM 2160
#define C_DIM 3
#define TPB 192
#define NSEG 5            // 192 threads * 5 float4 * 4 = 3840 cols = one full row

typedef float f32x4 __attribute__((ext_vector_type(4)));
// 4-byte-aligned vector type: gfx950 global_load_dwordx4 only needs dword
// alignment, so we can load the 5-element window directly (no realign switch).
typedef float f32x4u __attribute__((ext_vector_type(4), aligned(4)));

// Horizontal lerp from an unaligned 4-vector + 1 scalar: out[j] = c0*a[j] + c1*a[j+1].
__device__ __forceinline__ f32x4 hlerp(f32x4u v, float s, float c0, float c1) {
    f32x4 out;
    out.x = c0 * v.x + c1 * v.y;
    out.y = c0 * v.y + c1 * v.z;
    out.z = c0 * v.z + c1 * v.w;
    out.w = c0 * v.w + c1 * s;
    return out;
}

// Scalar clamped+masked path for row-edge segments (few threads per row).
__device__ __forceinline__ f32x4 hblend_slow(const float* __restrict__ row,
                                             int base, float c0, float c1) {
    f32x4 res;
    float r4[4];
#pragma unroll
    for (int jj = 0; jj < 4; ++jj) {
        const int x0i = base + jj;
        const int x1i = x0i + 1;
        const float m0 = (x0i >= 0 && x0i < W_DIM) ? 1.0f : 0.0f;
        const float m1 = (x1i >= 0 && x1i < W_DIM) ? 1.0f : 0.0f;
        const int i0 = min(max(x0i, 0), W_DIM - 1);
        const int i1 = min(max(x1i, 0), W_DIM - 1);
        r4[jj] = c0 * m0 * row[i0] + c1 * m1 * row[i1];
    }
    res.x = r4[0]; res.y = r4[1]; res.z = r4[2]; res.w = r4[3];
    return res;
}

__global__ __launch_bounds__(TPB) void rts_kernel(
    const float* __restrict__ fs,          // (C, T=3, H, W)
    const float* __restrict__ row_shifts,  // (H,)
    const float* __restrict__ rts,         // (H/2,)
    float* __restrict__ out)               // (C, H, W)
{
    const int h   = blockIdx.x;
    const int c   = blockIdx.y;
    const int tid = threadIdx.x;

    // Per-row constants: x0 = w + K, w1 = frac(-shift).
    const float shift = row_shifts[h];
    const float negs  = -shift;
    const float Kf    = floorf(negs);
    const float w1    = negs - Kf;
    const int   K     = (int)Kf;
    const float c0    = 1.0f - w1;
    const float c1    = w1;

    float a = 0.0f;
    if (h & 1) a = rts[h >> 1];
    const float ab = fabsf(a);
    const float cw = 1.0f - ab;

    const size_t frame_stride = (size_t)H_DIM * W_DIM;
    const float* curRow = fs + ((size_t)c * 3 + 1) * frame_stride + (size_t)h * W_DIM;
    const float* othRow = (a < 0.0f) ? (curRow - frame_stride)   // prev
                                     : (curRow + frame_stride);  // nxt
    float* outRow = out + ((size_t)c * H_DIM + h) * W_DIM;

    if (ab == 0.0f) {
        // Even rows (alpha==0): pure shifted copy of cur.
#pragma unroll
        for (int j = 0; j < NSEG; ++j) {
            const int w0   = 4 * (tid + j * TPB);
            const int base = w0 + K;
            f32x4 res;
            if (base >= 0 && base <= W_DIM - 5) {
                const f32x4u v = *(const f32x4u*)(curRow + base);
                const float  s = curRow[base + 4];
                res = hlerp(v, s, c0, c1);
            } else {
                res = hblend_slow(curRow, base, c0, c1);
            }
            __builtin_nontemporal_store(res, (f32x4*)(outRow + w0));
        }
    } else {
        // Odd rows: blend shifted cur with shifted prev/nxt.
#pragma unroll
        for (int j = 0; j < NSEG; ++j) {
            const int w0   = 4 * (tid + j * TPB);
            const int base = w0 + K;
            f32x4 res;
            if (base >= 0 && base <= W_DIM - 5) {
                const f32x4u cv = *(const f32x4u*)(curRow + base);
                const float  cs = curRow[base + 4];
                const f32x4u ov = *(const f32x4u*)(othRow + base);
                const float  os = othRow[base + 4];
                const f32x4 cu = hlerp(cv, cs, c0, c1);
                const f32x4 ot = hlerp(ov, os, c0, c1);
                res = cw * cu + ab * ot;
            } else {
                const f32x4 cu = hblend_slow(curRow, base, c0, c1);
                const f32x4 ot = hblend_slow(othRow, base, c0, c1);
                res = cw * cu + ab * ot;
            }
            __builtin_nontemporal_store(res, (f32x4*)(outRow + w0));
        }
    }
}

extern "C" void kernel_launch(void* const* d_in, const int* in_sizes, int n_in,
                              void* d_out, int out_size, void* d_ws, size_t ws_size,
                              hipStream_t stream) {
    const float* fs = (const float*)d_in[0];
    const float* rs = (const float*)d_in[1];
    const float* rt = (const float*)d_in[2];
    float* out = (float*)d_out;

    dim3 grid(H_DIM, C_DIM);   // one block per (row, channel)
    rts_kernel<<<grid, TPB, 0, stream>>>(fs, rs, rt, out);
}